// Round 1
// baseline (163.484 us; speedup 1.0000x reference)
//
#include <hip/hip_runtime.h>
#include <hip/hip_bf16.h>

typedef __bf16 bf16x8 __attribute__((ext_vector_type(8)));
typedef float f32x16 __attribute__((ext_vector_type(16)));
typedef unsigned short ushort_t;

#define NSENT 8192
#define LSEQ  120
#define GBAGS 256
#define WDIM_ 50
#define DFILT 230
#define NCLS  53
// K layout: 3 taps x 64 (60 real + 4 pad) = 192 = 12 mfma k-steps of 16
#define KSTEPS 12
// B fragment table: [c=24][d=256][j=8] bf16  -> 98304 bytes
#define BFRAG_ELEMS (24*256*8)

static __device__ __forceinline__ ushort_t f2bf(float f) {
    unsigned int u = __float_as_uint(f);
    unsigned int lsb = (u >> 16) & 1u;
    u += 0x7fffu + lsb;
    return (ushort_t)(u >> 16);
}

// ---------------- kernel 0: repack Wc (230,1,3,60) into MFMA B-fragment layout ----------------
__global__ __launch_bounds__(256) void pcnn_prep_b(const float* __restrict__ Wc,
                                                   ushort_t* __restrict__ Bfrag) {
    int idx = blockIdx.x * 256 + threadIdx.x;
    if (idx >= BFRAG_ELEMS) return;
    int c   = idx >> 11;        // k-chunk of 8
    int rem = idx & 2047;
    int d   = rem >> 3;
    int j   = rem & 7;
    int k   = c * 8 + j;        // 0..191
    int dh  = k >> 6;           // tap 0..2
    int w   = k & 63;           // 0..63 (>=60 is pad)
    float val = (d < DFILT && w < 60) ? Wc[(d * 3 + dh) * 60 + w] : 0.0f;
    Bfrag[idx] = f2bf(val);
}

// ---------------- kernel 1: per-sentence conv + max_t + tanh -> sent (N x 230 fp32) ----------
// block = 1 sentence, 256 threads (4 waves). LDS: emb[130 rows][64 bf16] XOR-swizzled.
#define LROWS 130
__global__ __launch_bounds__(256) void pcnn_conv_sent(
    const int* __restrict__ x, const int* __restrict__ ld, const int* __restrict__ rd,
    const float* __restrict__ Wv, const float* __restrict__ pf1, const float* __restrict__ pf2,
    const ushort_t* __restrict__ Bfrag, const float* __restrict__ bc,
    float* __restrict__ sent) {

    __shared__ __align__(16) unsigned char semb[LROWS * 128];

    const int n    = blockIdx.x;
    const int tid  = threadIdx.x;
    const int wv   = tid >> 6;
    const int lane = tid & 63;
    const int lhalf = lane >> 5;
    const int l31   = lane & 31;

    // --- B fragments for this wave's two 32-wide d-tiles (global, L2-resident) ---
    bf16x8 Bf[2][KSTEPS];
    #pragma unroll
    for (int i = 0; i < 2; ++i) {
        int dcol = (wv * 2 + i) * 32 + l31;
        #pragma unroll
        for (int ks = 0; ks < KSTEPS; ++ks) {
            int c = ks * 2 + lhalf;
            Bf[i][ks] = *reinterpret_cast<const bf16x8*>(Bfrag + ((c * 256 + dcol) << 3));
        }
    }

    // --- zero the pad rows 120..129 (1280 B = 80 uint4) ---
    if (tid < 80) {
        reinterpret_cast<uint4*>(semb + 120 * 128)[tid] = uint4{0, 0, 0, 0};
    }
    // --- gather/stage embeddings: 120 rows x 2 half-rows of 32 bf16 ---
    if (tid < 240) {
        int l = tid >> 1, h = tid & 1;
        int tok = x[n * LSEQ + l];
        float v[32];
        const float* wr = Wv + tok * WDIM_;
        if (h == 0) {
            #pragma unroll
            for (int j = 0; j < 16; ++j) {
                float2 t2 = *reinterpret_cast<const float2*>(wr + 2 * j);
                v[2 * j] = t2.x; v[2 * j + 1] = t2.y;
            }
        } else {
            #pragma unroll
            for (int j = 0; j < 9; ++j) {
                float2 t2 = *reinterpret_cast<const float2*>(wr + 32 + 2 * j);
                v[2 * j] = t2.x; v[2 * j + 1] = t2.y;
            }
            int lp = ld[n * LSEQ + l], rp = rd[n * LSEQ + l];
            #pragma unroll
            for (int j = 0; j < 5; ++j) v[18 + j] = pf1[lp * 5 + j];
            #pragma unroll
            for (int j = 0; j < 5; ++j) v[23 + j] = pf2[rp * 5 + j];
            v[28] = v[29] = v[30] = v[31] = 0.0f;
        }
        #pragma unroll
        for (int ch = 0; ch < 4; ++ch) {
            ushort_t u8[8];
            #pragma unroll
            for (int j = 0; j < 8; ++j) u8[j] = f2bf(v[ch * 8 + j]);
            int w0 = h * 32 + ch * 8;
            int byteoff = l * 128 + ((w0 * 2) ^ ((l & 7) << 4));
            *reinterpret_cast<uint4*>(semb + byteoff) = *reinterpret_cast<const uint4*>(u8);
        }
    }
    __syncthreads();

    // --- main MFMA loops: 4 t-tiles x 2 d-tiles, K=192 ---
    float dmax0 = -1e30f, dmax1 = -1e30f;
    #pragma unroll
    for (int tt = 0; tt < 4; ++tt) {
        bf16x8 Af[KSTEPS];
        int trow = tt * 32 + l31;
        #pragma unroll
        for (int ks = 0; ks < KSTEPS; ++ks) {
            int dh = ks >> 2, q = ks & 3;
            int l = trow + dh;
            int w0 = q * 16 + lhalf * 8;
            int byteoff = l * 128 + ((w0 * 2) ^ ((l & 7) << 4));
            Af[ks] = *reinterpret_cast<const bf16x8*>(semb + byteoff);
        }
        #pragma unroll
        for (int i = 0; i < 2; ++i) {
            f32x16 acc;
            #pragma unroll
            for (int r = 0; r < 16; ++r) acc[r] = 0.0f;
            #pragma unroll
            for (int ks = 0; ks < KSTEPS; ++ks)
                acc = __builtin_amdgcn_mfma_f32_32x32x16_bf16(Af[ks], Bf[i][ks], acc, 0, 0, 0);
            float m = -1e30f;
            #pragma unroll
            for (int r = 0; r < 16; ++r) {
                int t = tt * 32 + (r & 3) + 8 * (r >> 2) + 4 * lhalf;
                if (t < LSEQ - 2) m = fmaxf(m, acc[r]);
            }
            if (i == 0) dmax0 = fmaxf(dmax0, m);
            else        dmax1 = fmaxf(dmax1, m);
        }
    }
    dmax0 = fmaxf(dmax0, __shfl_xor(dmax0, 32));
    dmax1 = fmaxf(dmax1, __shfl_xor(dmax1, 32));
    if (lhalf == 0) {
        int d0 = (wv * 2 + 0) * 32 + l31;
        int d1 = (wv * 2 + 1) * 32 + l31;
        if (d0 < DFILT) sent[n * DFILT + d0] = tanhf(dmax0 + bc[d0]);
        if (d1 < DFILT) sent[n * DFILT + d1] = tanhf(dmax1 + bc[d1]);
    }
}

// ---------------- kernel 2: per-bag attention + scores + diag softmax ----------------
// scores[c,k] = sum_i alpha[i,c]*(e[i,k]-br[k]) + br[k]   (bag tensor eliminated)
#define MAXNS 32
__global__ __launch_bounds__(256) void pcnn_bag(
    const float* __restrict__ sent, const float* __restrict__ Wr, const float* __restrict__ br,
    const int* __restrict__ tshape, float* __restrict__ out) {

    __shared__ float s_sent[MAXNS * DFILT];   // 29440 B
    __shared__ float s_e[MAXNS * NCLS];       //  6784 B
    __shared__ float s_alpha[MAXNS * NCLS];   //  6784 B
    __shared__ float s_sc[NCLS * NCLS];       // 11236 B

    const int g = blockIdx.x;
    const int tid = threadIdx.x;
    int start = tshape[g], end = tshape[g + 1];
    int ns = end - start;
    if (ns > MAXNS) ns = MAXNS;

    for (int idx = tid; idx < ns * DFILT; idx += 256)
        s_sent[idx] = sent[start * DFILT + idx];
    __syncthreads();

    // e = sent @ Wr^T + br
    for (int task = tid; task < ns * NCLS; task += 256) {
        int i = task / NCLS, c = task - i * NCLS;
        const float* sp = s_sent + i * DFILT;
        const float* wp = Wr + c * DFILT;
        float acc = 0.0f;
        for (int d = 0; d < DFILT; ++d) acc = fmaf(sp[d], wp[d], acc);
        s_e[task] = acc + br[c];
    }
    __syncthreads();

    // per-class softmax over sentences -> alpha
    if (tid < NCLS) {
        int c = tid;
        float m = -1e30f;
        for (int i = 0; i < ns; ++i) m = fmaxf(m, s_e[i * NCLS + c]);
        float den = 0.0f;
        for (int i = 0; i < ns; ++i) {
            float ex = expf(s_e[i * NCLS + c] - m);
            s_alpha[i * NCLS + c] = ex;
            den += ex;
        }
        float inv = 1.0f / den;
        for (int i = 0; i < ns; ++i) s_alpha[i * NCLS + c] *= inv;
    }
    __syncthreads();

    // scores[c,k] = sum_i alpha[i,c]*(e[i,k]-br[k]) + br[k]
    for (int task = tid; task < NCLS * NCLS; task += 256) {
        int c = task / NCLS, k = task - (task / NCLS) * NCLS;
        float brk = br[k];
        float acc = 0.0f;
        for (int i = 0; i < ns; ++i)
            acc = fmaf(s_alpha[i * NCLS + c], s_e[i * NCLS + k] - brk, acc);
        s_sc[task] = acc + brk;
    }
    __syncthreads();

    // row softmax, take diagonal
    if (tid < NCLS) {
        int c = tid;
        float m = -1e30f;
        for (int k = 0; k < NCLS; ++k) m = fmaxf(m, s_sc[c * NCLS + k]);
        float den = 0.0f;
        for (int k = 0; k < NCLS; ++k) den += expf(s_sc[c * NCLS + k] - m);
        out[g * NCLS + c] = expf(s_sc[c * NCLS + c] - m) / den;
    }
}

extern "C" void kernel_launch(void* const* d_in, const int* in_sizes, int n_in,
                              void* d_out, int out_size, void* d_ws, size_t ws_size,
                              hipStream_t stream) {
    const int*   x   = (const int*)d_in[0];
    const int*   ldi = (const int*)d_in[1];
    const int*   rdi = (const int*)d_in[2];
    const int*   ts  = (const int*)d_in[3];
    const float* Wv  = (const float*)d_in[4];
    const float* pf1 = (const float*)d_in[5];
    const float* pf2 = (const float*)d_in[6];
    const float* Wc  = (const float*)d_in[7];
    const float* bc  = (const float*)d_in[8];
    const float* Wr  = (const float*)d_in[9];
    const float* br  = (const float*)d_in[10];
    float* out = (float*)d_out;

    ushort_t* Bfrag = (ushort_t*)d_ws;
    float* sent = (float*)((char*)d_ws + BFRAG_ELEMS * sizeof(ushort_t)); // 98304 B offset

    pcnn_prep_b<<<(BFRAG_ELEMS + 255) / 256, 256, 0, stream>>>(Wc, Bfrag);
    pcnn_conv_sent<<<NSENT, 256, 0, stream>>>(x, ldi, rdi, Wv, pf1, pf2, Bfrag, bc, sent);
    pcnn_bag<<<GBAGS, 256, 0, stream>>>(sent, Wr, br, ts, out);
}

// Round 2
// 150.526 us; speedup vs baseline: 1.0861x; 1.0861x over previous
//
#include <hip/hip_runtime.h>
#include <hip/hip_bf16.h>

typedef __bf16 bf16x8 __attribute__((ext_vector_type(8)));
typedef float f32x16 __attribute__((ext_vector_type(16)));
typedef unsigned short ushort_t;

#define NSENT 8192
#define LSEQ  120
#define GBAGS 256
#define WDIM_ 50
#define DFILT 230
#define NCLS  53
#define KSTEPS 12
#define BFRAG_ELEMS (24*256*8)
#define LROWS 130
#define SPB 4                      // sentences per block

static __device__ __forceinline__ ushort_t f2bf(float f) {
    unsigned int u = __float_as_uint(f);
    unsigned int lsb = (u >> 16) & 1u;
    u += 0x7fffu + lsb;
    return (ushort_t)(u >> 16);
}

// ---------------- kernel 0: repack Wc (230,1,3,60) into MFMA B-fragment layout ----------------
__global__ __launch_bounds__(256) void pcnn_prep_b(const float* __restrict__ Wc,
                                                   ushort_t* __restrict__ Bfrag) {
    int idx = blockIdx.x * 256 + threadIdx.x;
    if (idx >= BFRAG_ELEMS) return;
    int c   = idx >> 11;
    int rem = idx & 2047;
    int d   = rem >> 3;
    int j   = rem & 7;
    int k   = c * 8 + j;
    int dh  = k >> 6;
    int w   = k & 63;
    float val = (d < DFILT && w < 60) ? Wc[(d * 3 + dh) * 60 + w] : 0.0f;
    Bfrag[idx] = f2bf(val);
}

// ---------------- conv helpers ----------------
__device__ __forceinline__ void conv_gather(unsigned char* __restrict__ buf, int n,
    const int* __restrict__ x, const int* __restrict__ ld, const int* __restrict__ rd,
    const float* __restrict__ Wv, const float* __restrict__ pf1, const float* __restrict__ pf2,
    int tid) {
    if (tid >= 240) return;
    int l = tid >> 1, h = tid & 1;
    int tok = x[n * LSEQ + l];
    float v[32];
    const float* wr = Wv + tok * WDIM_;
    if (h == 0) {
        #pragma unroll
        for (int j = 0; j < 16; ++j) {
            float2 t2 = *reinterpret_cast<const float2*>(wr + 2 * j);
            v[2 * j] = t2.x; v[2 * j + 1] = t2.y;
        }
    } else {
        #pragma unroll
        for (int j = 0; j < 9; ++j) {
            float2 t2 = *reinterpret_cast<const float2*>(wr + 32 + 2 * j);
            v[2 * j] = t2.x; v[2 * j + 1] = t2.y;
        }
        int lp = ld[n * LSEQ + l], rp = rd[n * LSEQ + l];
        #pragma unroll
        for (int j = 0; j < 5; ++j) v[18 + j] = pf1[lp * 5 + j];
        #pragma unroll
        for (int j = 0; j < 5; ++j) v[23 + j] = pf2[rp * 5 + j];
        v[28] = v[29] = v[30] = v[31] = 0.0f;
    }
    #pragma unroll
    for (int ch = 0; ch < 4; ++ch) {
        ushort_t u8[8];
        #pragma unroll
        for (int j = 0; j < 8; ++j) u8[j] = f2bf(v[ch * 8 + j]);
        int w0 = h * 32 + ch * 8;
        int byteoff = l * 128 + ((w0 * 2) ^ ((l & 7) << 4));
        *reinterpret_cast<uint4*>(buf + byteoff) = *reinterpret_cast<const uint4*>(u8);
    }
}

__device__ __forceinline__ void conv_compute(const unsigned char* __restrict__ buf, int n,
    const bf16x8 (&Bf)[2][KSTEPS], const float* __restrict__ bc, float* __restrict__ sent,
    int wv, int lhalf, int l31) {
    float dmax0 = -1e30f, dmax1 = -1e30f;
    #pragma unroll
    for (int tt = 0; tt < 4; ++tt) {
        f32x16 acc0, acc1;
        #pragma unroll
        for (int r = 0; r < 16; ++r) { acc0[r] = 0.0f; acc1[r] = 0.0f; }
        int trow = tt * 32 + l31;
        #pragma unroll
        for (int ks = 0; ks < KSTEPS; ++ks) {
            int dh = ks >> 2, q = ks & 3;
            int l = trow + dh;
            int w0 = q * 16 + lhalf * 8;
            int byteoff = l * 128 + ((w0 * 2) ^ ((l & 7) << 4));
            bf16x8 Af = *reinterpret_cast<const bf16x8*>(buf + byteoff);
            acc0 = __builtin_amdgcn_mfma_f32_32x32x16_bf16(Af, Bf[0][ks], acc0, 0, 0, 0);
            acc1 = __builtin_amdgcn_mfma_f32_32x32x16_bf16(Af, Bf[1][ks], acc1, 0, 0, 0);
        }
        #pragma unroll
        for (int r = 0; r < 16; ++r) {
            int t = tt * 32 + (r & 3) + 8 * (r >> 2) + 4 * lhalf;
            bool valid = (tt < 3) || (t < LSEQ - 2);
            if (valid) { dmax0 = fmaxf(dmax0, acc0[r]); dmax1 = fmaxf(dmax1, acc1[r]); }
        }
    }
    dmax0 = fmaxf(dmax0, __shfl_xor(dmax0, 32));
    dmax1 = fmaxf(dmax1, __shfl_xor(dmax1, 32));
    if (lhalf == 0) {
        int d0 = (wv * 2 + 0) * 32 + l31;
        int d1 = (wv * 2 + 1) * 32 + l31;
        if (d0 < DFILT) sent[n * DFILT + d0] = tanhf(dmax0 + bc[d0]);
        if (d1 < DFILT) sent[n * DFILT + d1] = tanhf(dmax1 + bc[d1]);
    }
}

// ---------------- kernel 1: 4 sentences/block, double-buffered LDS pipeline ----------------
__global__ __launch_bounds__(256) void pcnn_conv_sent(
    const int* __restrict__ x, const int* __restrict__ ld, const int* __restrict__ rd,
    const float* __restrict__ Wv, const float* __restrict__ pf1, const float* __restrict__ pf2,
    const ushort_t* __restrict__ Bfrag, const float* __restrict__ bc,
    float* __restrict__ sent) {

    __shared__ __align__(16) unsigned char sembA[LROWS * 128];
    __shared__ __align__(16) unsigned char sembB[LROWS * 128];

    const int n0   = blockIdx.x * SPB;
    const int tid  = threadIdx.x;
    const int wv   = tid >> 6;
    const int lane = tid & 63;
    const int lhalf = lane >> 5;
    const int l31   = lane & 31;

    // B fragments: this wave's two 32-wide d-tiles, loaded once per block
    bf16x8 Bf[2][KSTEPS];
    #pragma unroll
    for (int i = 0; i < 2; ++i) {
        int dcol = (wv * 2 + i) * 32 + l31;
        #pragma unroll
        for (int ks = 0; ks < KSTEPS; ++ks) {
            int c = ks * 2 + lhalf;
            Bf[i][ks] = *reinterpret_cast<const bf16x8*>(Bfrag + ((c * 256 + dcol) << 3));
        }
    }

    // zero pad rows 120..129 of BOTH buffers (never overwritten afterwards)
    if (tid < 160) {
        int b = tid / 80, j = tid % 80;
        unsigned char* base = (b == 0 ? sembA : sembB) + 120 * 128;
        reinterpret_cast<uint4*>(base)[j] = uint4{0, 0, 0, 0};
    }
    conv_gather(sembA, n0 + 0, x, ld, rd, Wv, pf1, pf2, tid);
    __syncthreads();

    // s=0: gather s1->B, compute s0 from A
    conv_gather(sembB, n0 + 1, x, ld, rd, Wv, pf1, pf2, tid);
    conv_compute(sembA, n0 + 0, Bf, bc, sent, wv, lhalf, l31);
    __syncthreads();
    // s=1: gather s2->A, compute s1 from B
    conv_gather(sembA, n0 + 2, x, ld, rd, Wv, pf1, pf2, tid);
    conv_compute(sembB, n0 + 1, Bf, bc, sent, wv, lhalf, l31);
    __syncthreads();
    // s=2: gather s3->B, compute s2 from A
    conv_gather(sembB, n0 + 3, x, ld, rd, Wv, pf1, pf2, tid);
    conv_compute(sembA, n0 + 2, Bf, bc, sent, wv, lhalf, l31);
    __syncthreads();
    // s=3: compute s3 from B
    conv_compute(sembB, n0 + 3, Bf, bc, sent, wv, lhalf, l31);
}

// ---------------- kernel 2: per-bag attention + scores + diag softmax ----------------
#define MAXNS 32
#define CPAD 56
__global__ __launch_bounds__(256) void pcnn_bag(
    const float* __restrict__ sent, const float* __restrict__ Wr, const float* __restrict__ br,
    const int* __restrict__ tshape, float* __restrict__ out) {

    __shared__ float s_sent[MAXNS * DFILT];   // 29440 B
    __shared__ float s_Wr[NCLS * DFILT];      // 48760 B
    __shared__ float s_e[MAXNS * CPAD];       //  7168 B
    __shared__ float s_alpha[MAXNS * CPAD];   //  7168 B
    __shared__ float s_sc[NCLS * NCLS];       // 11236 B
    __shared__ float s_br[CPAD];

    const int g = blockIdx.x;
    const int tid = threadIdx.x;
    int start = tshape[g], end = tshape[g + 1];
    int ns = end - start;
    if (ns > MAXNS) ns = MAXNS;

    // stage sent rows (float2: 230*4 B rows keep 8B alignment) and Wr
    {
        int n2 = ns * (DFILT / 2);
        const float2* src = reinterpret_cast<const float2*>(sent + start * DFILT);
        for (int idx = tid; idx < n2; idx += 256)
            reinterpret_cast<float2*>(s_sent)[idx] = src[idx];
        const float2* wsrc = reinterpret_cast<const float2*>(Wr);
        for (int idx = tid; idx < (NCLS * DFILT) / 2; idx += 256)
            reinterpret_cast<float2*>(s_Wr)[idx] = wsrc[idx];
        if (tid < NCLS) s_br[tid] = br[tid];
    }
    __syncthreads();

    // e = sent @ Wr^T + br, 2x4 register-blocked (16 x 14 tasks)
    if (tid < 224) {
        int i0 = tid / 14, c0 = tid % 14;
        float a00 = 0, a01 = 0, a02 = 0, a03 = 0;
        float a10 = 0, a11 = 0, a12 = 0, a13 = 0;
        const float* s0p = s_sent + (2 * i0) * DFILT;
        const float* s1p = s_sent + (2 * i0 + 1) * DFILT;
        const float* w0p = s_Wr + (4 * c0 + 0) * DFILT;
        const float* w1p = s_Wr + (4 * c0 + 1) * DFILT;
        const float* w2p = (4 * c0 + 2 < NCLS) ? s_Wr + (4 * c0 + 2) * DFILT : s_Wr;
        const float* w3p = (4 * c0 + 3 < NCLS) ? s_Wr + (4 * c0 + 3) * DFILT : s_Wr;
        for (int d = 0; d < DFILT; ++d) {
            float s0 = s0p[d], s1 = s1p[d];
            float w0 = w0p[d], w1 = w1p[d], w2 = w2p[d], w3 = w3p[d];
            a00 = fmaf(s0, w0, a00); a01 = fmaf(s0, w1, a01);
            a02 = fmaf(s0, w2, a02); a03 = fmaf(s0, w3, a03);
            a10 = fmaf(s1, w0, a10); a11 = fmaf(s1, w1, a11);
            a12 = fmaf(s1, w2, a12); a13 = fmaf(s1, w3, a13);
        }
        float av[2][4] = {{a00, a01, a02, a03}, {a10, a11, a12, a13}};
        #pragma unroll
        for (int ii = 0; ii < 2; ++ii) {
            int i = 2 * i0 + ii;
            #pragma unroll
            for (int j = 0; j < 4; ++j) {
                int c = 4 * c0 + j;
                if (i < ns && c < NCLS) s_e[i * CPAD + c] = av[ii][j] + s_br[c];
            }
        }
    }
    __syncthreads();

    // per-class softmax over sentences -> alpha
    if (tid < NCLS) {
        int c = tid;
        float m = -1e30f;
        for (int i = 0; i < ns; ++i) m = fmaxf(m, s_e[i * CPAD + c]);
        float den = 0.0f;
        for (int i = 0; i < ns; ++i) {
            float ex = expf(s_e[i * CPAD + c] - m);
            s_alpha[i * CPAD + c] = ex;
            den += ex;
        }
        float inv = 1.0f / den;
        for (int i = 0; i < ns; ++i) s_alpha[i * CPAD + c] *= inv;
    }
    __syncthreads();

    // scores[c,k] = sum_i alpha[i,c]*(e[i,k]-br[k]) + br[k], 4-wide k blocking (53x14 tasks)
    for (int task = tid; task < NCLS * 14; task += 256) {
        int c = task / 14, k0 = (task % 14) * 4;
        float b0 = s_br[k0], b1 = (k0+1<NCLS)?s_br[k0+1]:0.f, b2 = (k0+2<NCLS)?s_br[k0+2]:0.f, b3 = (k0+3<NCLS)?s_br[k0+3]:0.f;
        float a0 = 0, a1 = 0, a2 = 0, a3 = 0;
        for (int i = 0; i < ns; ++i) {
            float al = s_alpha[i * CPAD + c];
            const float* ep = s_e + i * CPAD + k0;
            a0 = fmaf(al, ep[0] - b0, a0);
            a1 = fmaf(al, (k0+1<NCLS?ep[1]:0.f) - b1, a1);
            a2 = fmaf(al, (k0+2<NCLS?ep[2]:0.f) - b2, a2);
            a3 = fmaf(al, (k0+3<NCLS?ep[3]:0.f) - b3, a3);
        }
        if (k0 + 0 < NCLS) s_sc[c * NCLS + k0 + 0] = a0 + b0;
        if (k0 + 1 < NCLS) s_sc[c * NCLS + k0 + 1] = a1 + b1;
        if (k0 + 2 < NCLS) s_sc[c * NCLS + k0 + 2] = a2 + b2;
        if (k0 + 3 < NCLS) s_sc[c * NCLS + k0 + 3] = a3 + b3;
    }
    __syncthreads();

    // row softmax, take diagonal
    if (tid < NCLS) {
        int c = tid;
        float m = -1e30f;
        for (int k = 0; k < NCLS; ++k) m = fmaxf(m, s_sc[c * NCLS + k]);
        float den = 0.0f;
        for (int k = 0; k < NCLS; ++k) den += expf(s_sc[c * NCLS + k] - m);
        out[g * NCLS + c] = expf(s_sc[c * NCLS + c] - m) / den;
    }
}

extern "C" void kernel_launch(void* const* d_in, const int* in_sizes, int n_in,
                              void* d_out, int out_size, void* d_ws, size_t ws_size,
                              hipStream_t stream) {
    const int*   x   = (const int*)d_in[0];
    const int*   ldi = (const int*)d_in[1];
    const int*   rdi = (const int*)d_in[2];
    const int*   ts  = (const int*)d_in[3];
    const float* Wv  = (const float*)d_in[4];
    const float* pf1 = (const float*)d_in[5];
    const float* pf2 = (const float*)d_in[6];
    const float* Wc  = (const float*)d_in[7];
    const float* bc  = (const float*)d_in[8];
    const float* Wr  = (const float*)d_in[9];
    const float* br  = (const float*)d_in[10];
    float* out = (float*)d_out;

    ushort_t* Bfrag = (ushort_t*)d_ws;
    float* sent = (float*)((char*)d_ws + BFRAG_ELEMS * sizeof(ushort_t));

    pcnn_prep_b<<<(BFRAG_ELEMS + 255) / 256, 256, 0, stream>>>(Wc, Bfrag);
    pcnn_conv_sent<<<NSENT / SPB, 256, 0, stream>>>(x, ldi, rdi, Wv, pf1, pf2, Bfrag, bc, sent);
    pcnn_bag<<<GBAGS, 256, 0, stream>>>(sent, Wr, br, ts, out);
}